// Round 7
// baseline (230.614 us; speedup 1.0000x reference)
//
#include <hip/hip_runtime.h>
#include <stdint.h>
#include <math.h>

// Problem constants (B=8192 rows, D=512 features)
#define Bn 8192
#define Dn 512
#define EPSN 1e-12f
#define EPSP 1e-6f
#define MARG 0.3f

// GEMM (R7): block 128x128, 4 waves 2x2, wave tile 64x64, BK=32.
// A: swizzled global_load_lds dbuf (R5-verified, 0 conflicts).
// B: direct global->VGPR fragment loads with 1-iter register prefetch
//    (halves LDS reads and staging writes; B served from L2 - consecutive
//    blocks share the col-tile so its 128 KB panel stays hot).
// R1-R6 model: perf = min over (latency-hiding TLP, LDS-pipe); R5's 64x64
// tile @ 4 blk/CU was the LDS-in-the-loop optimum (116us); R6's occ=62% with
// worse reads/FLOP regressed (158us). This cuts the LDS leg instead.
#define BM 128
#define BN 128
#define BK 32
#define KT (Dn / BK)    // 16 k-iterations
#define NCT (Bn / BN)   // 64 column tiles
#define NRT (Bn / BM)   // 64 row tiles

typedef short bf16x8 __attribute__((ext_vector_type(8)));  // 8 bf16 (4 VGPRs)
typedef float f32x4  __attribute__((ext_vector_type(4)));

__device__ __forceinline__ uint16_t f2bf(float f) {
    union { float f; uint32_t u; } c; c.f = f;
    uint32_t r = (c.u + 0x7fffu + ((c.u >> 16) & 1u)) >> 16;  // RNE
    return (uint16_t)r;
}

// async global->LDS, 16B per lane; LDS dest is wave-uniform base + lane*16
__device__ __forceinline__ void async16(const void* g, void* l) {
    __builtin_amdgcn_global_load_lds(
        (const __attribute__((address_space(1))) void*)g,
        (__attribute__((address_space(3))) void*)l,
        16, 0, 0);
}

// ---------------------------------------------------------------------------
// K1: per-row L2 normalize -> bf16 rows, inverse norms, column term
// c[j] = -sp2[j] + 2*eps*sp[j]. One wave per 512-float row, 16384 rows.
// ---------------------------------------------------------------------------
__global__ __launch_bounds__(256) void k_normalize(
    const float* __restrict__ x,
    uint16_t* __restrict__ a_bf, uint16_t* __restrict__ p_bf,
    float* __restrict__ rnA, float* __restrict__ rnP,
    float* __restrict__ cterm)
{
    const int wave = threadIdx.x >> 6;
    const int lane = threadIdx.x & 63;
    const int r = blockIdx.x * 4 + wave;   // 0..16383
    const int i = r >> 1;
    const int which = r & 1;               // 0 = a-row, 1 = p-row

    const float* src = x + (size_t)i * (2 * Dn) + (size_t)which * Dn + lane * 8;
    float4 lo = ((const float4*)src)[0];
    float4 hi = ((const float4*)src)[1];
    float v[8] = {lo.x, lo.y, lo.z, lo.w, hi.x, hi.y, hi.z, hi.w};

    float ss = 0.f;
#pragma unroll
    for (int j = 0; j < 8; ++j) ss += v[j] * v[j];
#pragma unroll
    for (int m = 1; m < 64; m <<= 1) ss += __shfl_xor(ss, m);
    const float scale = 1.0f / fmaxf(sqrtf(ss), EPSN);

    float o[8], s1 = 0.f, s2 = 0.f;
#pragma unroll
    for (int j = 0; j < 8; ++j) { o[j] = v[j] * scale; s1 += o[j]; s2 += o[j] * o[j]; }

    uint16_t* bdst = (which ? p_bf : a_bf) + (size_t)i * Dn + lane * 8;
    bf16x8 bb;
#pragma unroll
    for (int j = 0; j < 8; ++j) bb[j] = (short)f2bf(o[j]);
    *(bf16x8*)bdst = bb;

    if (which) {
#pragma unroll
        for (int m = 1; m < 64; m <<= 1) { s1 += __shfl_xor(s1, m); s2 += __shfl_xor(s2, m); }
        if (lane == 0) { cterm[i] = -s2 + 2.0f * EPSP * s1; rnP[i] = scale; }
    } else {
        if (lane == 0) rnA[i] = scale;
    }
}

// ---------------------------------------------------------------------------
// K2: bf16 MFMA GEMM (a_n @ p_n^T) + fused per-row argmax.
// A via XOR-swizzled LDS dbuf; B fragments direct global->VGPR, prefetched
// one iter ahead (issued right after the barrier -> L2 latency hides under
// the compute phase). Per block-iter: LDS 16 KB read + 8 KB write (~290 cyc)
// vs 64 MFMA (~310 cyc) -- LDS no longer the long pole.
// ---------------------------------------------------------------------------
__global__ __launch_bounds__(256, 4) void k_gemm_argmax(
    const uint16_t* __restrict__ a_bf, const uint16_t* __restrict__ p_bf,
    const float* __restrict__ cterm,
    float* __restrict__ pval, int* __restrict__ pidx)
{
    __shared__ uint16_t As[2][BM * BK];   // 2 x 8 KB
    __shared__ float rv[2][BM];
    __shared__ int   ri[2][BM];

    const int t = threadIdx.x;
    const int wave = t >> 6;
    const int lane = t & 63;
    const int rowBase = blockIdx.x * BM;   // x = row-tile: consecutive blocks
    const int colBase = blockIdx.y * BN;   // share the col-tile's B panel (L2)

    const int q = lane >> 4;       // 0..3  (k-chunk)
    const int m16 = lane & 15;     // 0..15
    const int waveRow = (wave >> 1) * 64;
    const int waveCol = (wave & 1) * 64;

    // --- A staging pointers, hoisted. Chunks c0=t, c1=256+t (512 chunks).
    // Chunk c -> row c>>2, LDS slot c&3 holding global k-chunk (c&3)^((row>>1)&3).
    const int r0 = t >> 2;
    const int g0 = (t & 3) ^ ((r0 >> 1) & 3);
    const int r1 = (256 + t) >> 2;
    const int g1 = ((256 + t) & 3) ^ ((r1 >> 1) & 3);
    const uint16_t* gA0 = a_bf + (size_t)(rowBase + r0) * Dn + g0 * 8;
    const uint16_t* gA1 = a_bf + (size_t)(rowBase + r1) * Dn + g1 * 8;
    const int ldsC0 = (wave * 64) * 8;           // wave-uniform LDS dest bases
    const int ldsC1 = (256 + wave * 64) * 8;     // (HW adds lane*16)

    // --- A fragment LDS read base: slot = q ^ ((m16>>1)&3) for all mt
    const int s0 = q ^ ((m16 >> 1) & 3);
    const int aBase = (waveRow + m16) * BK + s0 * 8;

    // --- B fragment global pointers: col n = m16 within each 16-col group,
    // k-chunk q -> quad lanes read 64 B contiguous of one B row.
    const uint16_t* pB[4];
#pragma unroll
    for (int nt = 0; nt < 4; ++nt)
        pB[nt] = p_bf + (size_t)(colBase + waveCol + nt * 16 + m16) * Dn + q * 8;

    f32x4 acc[4][4];
#pragma unroll
    for (int a = 0; a < 4; ++a)
#pragma unroll
        for (int b = 0; b < 4; ++b) acc[a][b] = (f32x4){0.f, 0.f, 0.f, 0.f};

    auto stageA = [&](int buf, int ke) {
        async16(gA0 + ke, &As[buf][ldsC0]);
        async16(gA1 + ke, &As[buf][ldsC1]);
    };

    stageA(0, 0);
    bf16x8 bcur[4], bnext[4];
#pragma unroll
    for (int nt = 0; nt < 4; ++nt) bcur[nt] = *(const bf16x8*)(pB[nt]);

#pragma unroll
    for (int kt = 0; kt < KT; ++kt) {
        const int cur = kt & 1;
        __syncthreads();                 // A tile kt resident; prior buf reads done
        if (kt + 1 < KT) {
            stageA(cur ^ 1, (kt + 1) * BK);   // A prefetch: drains at NEXT barrier
#pragma unroll
            for (int nt = 0; nt < 4; ++nt)    // B prefetch: kt*64B folds into imm
                bnext[nt] = *(const bf16x8*)(pB[nt] + (kt + 1) * BK);
        }

        const uint16_t* pa = &As[cur][aBase];
        bf16x8 af[4];
#pragma unroll
        for (int mt = 0; mt < 4; ++mt)
            af[mt] = *(const bf16x8*)(pa + mt * 16 * BK);
#pragma unroll
        for (int mt = 0; mt < 4; ++mt)
#pragma unroll
            for (int nt = 0; nt < 4; ++nt)
                acc[mt][nt] = __builtin_amdgcn_mfma_f32_16x16x32_bf16(
                    af[mt], bcur[nt], acc[mt][nt], 0, 0, 0);
#pragma unroll
        for (int nt = 0; nt < 4; ++nt) bcur[nt] = bnext[nt];  // renamed by unroll
    }

    // epilogue: score = 2*dot + c[j]; mask diagonal; per-row argmax
    float cv[4];
#pragma unroll
    for (int nt = 0; nt < 4; ++nt)
        cv[nt] = cterm[colBase + waveCol + nt * 16 + m16];

#pragma unroll
    for (int mt = 0; mt < 4; ++mt) {
#pragma unroll
        for (int v = 0; v < 4; ++v) {
            const int lr = waveRow + mt * 16 + q * 4 + v;   // C/D row = quad*4+reg
            const int gi = rowBase + lr;
            float best = -INFINITY;
            int bidx = 0x7fffffff;
#pragma unroll
            for (int nt = 0; nt < 4; ++nt) {
                const int gj = colBase + waveCol + nt * 16 + m16;  // col = lane&15
                float sc = 2.0f * acc[mt][nt][v] + cv[nt];
                if (gj == gi) sc = -INFINITY;
                if (sc > best || (sc == best && gj < bidx)) { best = sc; bidx = gj; }
            }
#pragma unroll
            for (int msk = 1; msk < 16; msk <<= 1) {       // reduce over 16 cols
                float ob = __shfl_xor(best, msk);
                int oi = __shfl_xor(bidx, msk);
                if (ob > best || (ob == best && oi < bidx)) { best = ob; bidx = oi; }
            }
            if (m16 == 0) { rv[wave & 1][lr] = best; ri[wave & 1][lr] = bidx; }
        }
    }
    __syncthreads();
    if (t < BM) {
        float b0 = rv[0][t]; int i0 = ri[0][t];
        float b1 = rv[1][t]; int i1 = ri[1][t];
        if (b1 > b0 || (b1 == b0 && i1 < i0)) { b0 = b1; i0 = i1; }
        const size_t o = (size_t)(rowBase + t) * NCT + blockIdx.y;
        pval[o] = b0;
        pidx[o] = i0;
    }
}

// ---------------------------------------------------------------------------
// K3: reduce 64 partials -> negidx; recompute normalized rows from x + stored
// inverse norms; pos/neg distances fp32 per reference; relu -> rowloss.
// One wave per row.
// ---------------------------------------------------------------------------
__global__ __launch_bounds__(256) void k_rowloss(
    const float* __restrict__ x,
    const float* __restrict__ rnA, const float* __restrict__ rnP,
    const float* __restrict__ pval, const int* __restrict__ pidx,
    float* __restrict__ rowloss)
{
    const int wave = threadIdx.x >> 6;
    const int lane = threadIdx.x & 63;
    const int i = blockIdx.x * 4 + wave;

    float best = pval[(size_t)i * NCT + lane];
    int bidx = pidx[(size_t)i * NCT + lane];
#pragma unroll
    for (int msk = 1; msk < 64; msk <<= 1) {
        float ob = __shfl_xor(best, msk);
        int oi = __shfl_xor(bidx, msk);
        if (ob > best || (ob == best && oi < bidx)) { best = ob; bidx = oi; }
    }

    const float ra = rnA[i];
    const float rp = rnP[i];
    const float rn = rnP[bidx];
    const float4* av = (const float4*)(x + (size_t)i * (2 * Dn));
    const float4* pv = (const float4*)(x + (size_t)i * (2 * Dn) + Dn);
    const float4* nv = (const float4*)(x + (size_t)bidx * (2 * Dn) + Dn);
    float pos = 0.f, ng = 0.f;
#pragma unroll
    for (int c = 0; c < 2; ++c) {
        const int idx = lane + c * 64;
        float4 a4 = av[idx], p4 = pv[idx], n4 = nv[idx];
        float u;
        u = a4.x * ra - p4.x * rp + EPSP; pos += u * u;
        u = a4.y * ra - p4.y * rp + EPSP; pos += u * u;
        u = a4.z * ra - p4.z * rp + EPSP; pos += u * u;
        u = a4.w * ra - p4.w * rp + EPSP; pos += u * u;
        u = a4.x * ra - n4.x * rn + EPSP; ng += u * u;
        u = a4.y * ra - n4.y * rn + EPSP; ng += u * u;
        u = a4.z * ra - n4.z * rn + EPSP; ng += u * u;
        u = a4.w * ra - n4.w * rn + EPSP; ng += u * u;
    }
#pragma unroll
    for (int msk = 1; msk < 64; msk <<= 1) {
        pos += __shfl_xor(pos, msk);
        ng += __shfl_xor(ng, msk);
    }
    if (lane == 0) rowloss[i] = fmaxf(pos - ng + MARG, 0.f);
}

// ---------------------------------------------------------------------------
// K4: mean over 8192 row losses -> scalar out (deterministic, no atomics;
// R5 showed single-address device atomicAdd serializes ~100us across XCDs)
// ---------------------------------------------------------------------------
__global__ __launch_bounds__(1024) void k_final(
    const float* __restrict__ rowloss, float* __restrict__ out)
{
    __shared__ float sm[16];
    float s = 0.f;
    for (int k = threadIdx.x; k < Bn; k += 1024) s += rowloss[k];
#pragma unroll
    for (int msk = 1; msk < 64; msk <<= 1) s += __shfl_xor(s, msk);
    if ((threadIdx.x & 63) == 0) sm[threadIdx.x >> 6] = s;
    __syncthreads();
    if (threadIdx.x == 0) {
        float tot = 0.f;
#pragma unroll
        for (int w = 0; w < 16; ++w) tot += sm[w];
        out[0] = tot * (1.0f / Bn);
    }
}

extern "C" void kernel_launch(void* const* d_in, const int* in_sizes, int n_in,
                              void* d_out, int out_size, void* d_ws, size_t ws_size,
                              hipStream_t stream)
{
    const float* x = (const float*)d_in[0];
    char* ws = (char*)d_ws;
    // workspace layout (bytes):
    uint16_t* a_bf    = (uint16_t*)(ws + 0);         // 8 MB
    uint16_t* p_bf    = (uint16_t*)(ws + 8388608);   // 8 MB
    float*    rnA     = (float*)(ws + 16777216);     // 32 KB
    float*    rnP     = (float*)(ws + 16809984);     // 32 KB
    float*    cterm   = (float*)(ws + 16842752);     // 32 KB
    float*    pval    = (float*)(ws + 16875520);     // 2 MB
    int*      pidx    = (int*)(ws + 18972672);       // 2 MB
    float*    rowloss = (float*)(ws + 21069824);     // 32 KB (total ~21.1 MB)
    float*    out     = (float*)d_out;

    k_normalize<<<4096, 256, 0, stream>>>(x, a_bf, p_bf, rnA, rnP, cterm);
    k_gemm_argmax<<<dim3(NRT, NCT), 256, 0, stream>>>(a_bf, p_bf, cterm, pval, pidx);
    k_rowloss<<<2048, 256, 0, stream>>>(x, rnA, rnP, pval, pidx, rowloss);
    k_final<<<1, 1024, 0, stream>>>(rowloss, out);
}

// Round 8
// 186.224 us; speedup vs baseline: 1.2384x; 1.2384x over previous
//
#include <hip/hip_runtime.h>
#include <stdint.h>
#include <math.h>

// Problem constants (B=8192 rows, D=512 features)
#define Bn 8192
#define Dn 512
#define EPSN 1e-12f
#define EPSP 1e-6f
#define MARG 0.3f

// GEMM (R8 = R5's measured-best config): block 128x128, 4 waves 2x2, wave
// tile 64x64, BK=32, both operands via XOR-swizzled global_load_lds dbuf,
// __launch_bounds__(256,4) -> 4 blocks/CU. Measured R5: 116us, MfmaUtil 25,
// occ 42, 0 conflicts. Session evidence (R1-R7):
//   - occupancy lever: 2 blk/CU=162-203us, 3=138-140, 4=116, 6 blk w/ smaller
//     tile=158 (LDS reads/FLOP worsened) -> 4 blk @ 64x64 is the optimum.
//   - B out of LDS (R4 global->VGPR stream, R7 register prefetch): both lose;
//     LDS broadcast reuse + wave-uniform staging beats L2 round-trips.
//   - single-address device atomicAdd for the mean: +100us (XCD serialize).
// Remaining 2.1x over the 33us MFMA floor is the structural barrier drain
// (vmcnt(0) before s_barrier) - not addressable at HIP source level.
#define BM 128
#define BN 128
#define BK 32
#define KT (Dn / BK)    // 16 k-iterations
#define NCT (Bn / BN)   // 64 column tiles

typedef short bf16x8 __attribute__((ext_vector_type(8)));  // 8 bf16 (4 VGPRs)
typedef float f32x4  __attribute__((ext_vector_type(4)));

__device__ __forceinline__ uint16_t f2bf(float f) {
    union { float f; uint32_t u; } c; c.f = f;
    uint32_t r = (c.u + 0x7fffu + ((c.u >> 16) & 1u)) >> 16;  // RNE
    return (uint16_t)r;
}

// async global->LDS, 16B per lane; LDS dest is wave-uniform base + lane*16
__device__ __forceinline__ void async16(const void* g, void* l) {
    __builtin_amdgcn_global_load_lds(
        (const __attribute__((address_space(1))) void*)g,
        (__attribute__((address_space(3))) void*)l,
        16, 0, 0);
}

// ---------------------------------------------------------------------------
// K1: per-row L2 normalize -> bf16 rows, inverse norms, column term
// c[j] = -sp2[j] + 2*eps*sp[j]. One wave per 512-float row, 16384 rows.
// ---------------------------------------------------------------------------
__global__ __launch_bounds__(256) void k_normalize(
    const float* __restrict__ x,
    uint16_t* __restrict__ a_bf, uint16_t* __restrict__ p_bf,
    float* __restrict__ rnA, float* __restrict__ rnP,
    float* __restrict__ cterm)
{
    const int wave = threadIdx.x >> 6;
    const int lane = threadIdx.x & 63;
    const int r = blockIdx.x * 4 + wave;   // 0..16383
    const int i = r >> 1;
    const int which = r & 1;               // 0 = a-row, 1 = p-row

    const float* src = x + (size_t)i * (2 * Dn) + (size_t)which * Dn + lane * 8;
    float4 lo = ((const float4*)src)[0];
    float4 hi = ((const float4*)src)[1];
    float v[8] = {lo.x, lo.y, lo.z, lo.w, hi.x, hi.y, hi.z, hi.w};

    float ss = 0.f;
#pragma unroll
    for (int j = 0; j < 8; ++j) ss += v[j] * v[j];
#pragma unroll
    for (int m = 1; m < 64; m <<= 1) ss += __shfl_xor(ss, m);
    const float scale = 1.0f / fmaxf(sqrtf(ss), EPSN);

    float o[8], s1 = 0.f, s2 = 0.f;
#pragma unroll
    for (int j = 0; j < 8; ++j) { o[j] = v[j] * scale; s1 += o[j]; s2 += o[j] * o[j]; }

    uint16_t* bdst = (which ? p_bf : a_bf) + (size_t)i * Dn + lane * 8;
    bf16x8 bb;
#pragma unroll
    for (int j = 0; j < 8; ++j) bb[j] = (short)f2bf(o[j]);
    *(bf16x8*)bdst = bb;

    if (which) {
#pragma unroll
        for (int m = 1; m < 64; m <<= 1) { s1 += __shfl_xor(s1, m); s2 += __shfl_xor(s2, m); }
        if (lane == 0) { cterm[i] = -s2 + 2.0f * EPSP * s1; rnP[i] = scale; }
    } else {
        if (lane == 0) rnA[i] = scale;
    }
}

// ---------------------------------------------------------------------------
// K2: bf16 MFMA GEMM (a_n @ p_n^T) + fused per-row argmax over the 128-col
// tile. Exact R5 configuration (measured 116us).
// ---------------------------------------------------------------------------
__global__ __launch_bounds__(256, 4) void k_gemm_argmax(
    const uint16_t* __restrict__ a_bf, const uint16_t* __restrict__ p_bf,
    const float* __restrict__ cterm,
    float* __restrict__ pval, int* __restrict__ pidx)
{
    __shared__ uint16_t As[2][BM * BK];   // 2 x 8 KB
    __shared__ uint16_t Bs[2][BN * BK];   // 2 x 8 KB
    __shared__ float rv[2][BM];
    __shared__ int   ri[2][BM];

    const int t = threadIdx.x;
    const int wave = t >> 6;
    const int lane = t & 63;
    const int rowBase = blockIdx.y * BM;
    const int colBase = blockIdx.x * BN;

    const int q = lane >> 4;       // 0..3  (k-chunk)
    const int m16 = lane & 15;     // 0..15
    const int waveRow = (wave >> 1) * 64;
    const int waveCol = (wave & 1) * 64;

    // --- staging pointers, hoisted. Thread handles chunks c0=t, c1=256+t.
    // Chunk c -> row c>>2, LDS slot c&3 holding global k-chunk (c&3)^((row>>1)&3).
    const int r0 = t >> 2;
    const int g0 = (t & 3) ^ ((r0 >> 1) & 3);
    const int r1 = (256 + t) >> 2;
    const int g1 = ((256 + t) & 3) ^ ((r1 >> 1) & 3);
    const uint16_t* gA0 = a_bf + (size_t)(rowBase + r0) * Dn + g0 * 8;
    const uint16_t* gA1 = a_bf + (size_t)(rowBase + r1) * Dn + g1 * 8;
    const uint16_t* gB0 = p_bf + (size_t)(colBase + r0) * Dn + g0 * 8;
    const uint16_t* gB1 = p_bf + (size_t)(colBase + r1) * Dn + g1 * 8;
    // wave-uniform LDS dest bases (HW adds lane*16)
    const int ldsC0 = (wave * 64) * 8;           // elements
    const int ldsC1 = (256 + wave * 64) * 8;

    // --- fragment LDS read bases: slot = q ^ ((m16>>1)&3) for ALL mt/nt
    const int s0 = q ^ ((m16 >> 1) & 3);
    const int aBase = (waveRow + m16) * BK + s0 * 8;   // elements
    const int bBase = (waveCol + m16) * BK + s0 * 8;

    f32x4 acc[4][4];
#pragma unroll
    for (int a = 0; a < 4; ++a)
#pragma unroll
        for (int b = 0; b < 4; ++b) acc[a][b] = (f32x4){0.f, 0.f, 0.f, 0.f};

    // stage tile kt (k element offset = kt*32, an immediate after unroll)
    auto stage = [&](int buf, int ke) {
        async16(gA0 + ke, &As[buf][ldsC0]);
        async16(gA1 + ke, &As[buf][ldsC1]);
        async16(gB0 + ke, &Bs[buf][ldsC0]);
        async16(gB1 + ke, &Bs[buf][ldsC1]);
    };

    stage(0, 0);
#pragma unroll
    for (int kt = 0; kt < KT; ++kt) {
        const int cur = kt & 1;
        __syncthreads();                 // tile kt resident; prior buf reads done
        if (kt + 1 < KT) stage(cur ^ 1, (kt + 1) * BK);  // drains at NEXT barrier

        const uint16_t* pa = &As[cur][aBase];
        const uint16_t* pb = &Bs[cur][bBase];
        bf16x8 af[4], bfr[4];
#pragma unroll
        for (int mt = 0; mt < 4; ++mt)
            af[mt] = *(const bf16x8*)(pa + mt * 16 * BK);
#pragma unroll
        for (int nt = 0; nt < 4; ++nt)
            bfr[nt] = *(const bf16x8*)(pb + nt * 16 * BK);
#pragma unroll
        for (int mt = 0; mt < 4; ++mt)
#pragma unroll
            for (int nt = 0; nt < 4; ++nt)
                acc[mt][nt] = __builtin_amdgcn_mfma_f32_16x16x32_bf16(
                    af[mt], bfr[nt], acc[mt][nt], 0, 0, 0);
    }

    // epilogue: score = 2*dot + c[j]; mask diagonal; per-row argmax
    float cv[4];
#pragma unroll
    for (int nt = 0; nt < 4; ++nt)
        cv[nt] = cterm[colBase + waveCol + nt * 16 + m16];

#pragma unroll
    for (int mt = 0; mt < 4; ++mt) {
#pragma unroll
        for (int v = 0; v < 4; ++v) {
            const int lr = waveRow + mt * 16 + q * 4 + v;   // C/D row = quad*4+reg
            const int gi = rowBase + lr;
            float best = -INFINITY;
            int bidx = 0x7fffffff;
#pragma unroll
            for (int nt = 0; nt < 4; ++nt) {
                const int gj = colBase + waveCol + nt * 16 + m16;  // col = lane&15
                float sc = 2.0f * acc[mt][nt][v] + cv[nt];
                if (gj == gi) sc = -INFINITY;
                if (sc > best || (sc == best && gj < bidx)) { best = sc; bidx = gj; }
            }
#pragma unroll
            for (int msk = 1; msk < 16; msk <<= 1) {       // reduce over 16 cols
                float ob = __shfl_xor(best, msk);
                int oi = __shfl_xor(bidx, msk);
                if (ob > best || (ob == best && oi < bidx)) { best = ob; bidx = oi; }
            }
            if (m16 == 0) { rv[wave & 1][lr] = best; ri[wave & 1][lr] = bidx; }
        }
    }
    __syncthreads();
    if (t < BM) {
        float b0 = rv[0][t]; int i0 = ri[0][t];
        float b1 = rv[1][t]; int i1 = ri[1][t];
        if (b1 > b0 || (b1 == b0 && i1 < i0)) { b0 = b1; i0 = i1; }
        const size_t o = (size_t)(rowBase + t) * NCT + blockIdx.x;
        pval[o] = b0;
        pidx[o] = i0;
    }
}

// ---------------------------------------------------------------------------
// K3: reduce 64 partials -> negidx; recompute normalized rows from x + stored
// inverse norms; pos/neg distances fp32 per reference; relu -> rowloss.
// One wave per row. (Non-atomic: R5 showed single-address device atomicAdd
// serializes ~100us across XCDs.)
// ---------------------------------------------------------------------------
__global__ __launch_bounds__(256) void k_rowloss(
    const float* __restrict__ x,
    const float* __restrict__ rnA, const float* __restrict__ rnP,
    const float* __restrict__ pval, const int* __restrict__ pidx,
    float* __restrict__ rowloss)
{
    const int wave = threadIdx.x >> 6;
    const int lane = threadIdx.x & 63;
    const int i = blockIdx.x * 4 + wave;

    float best = pval[(size_t)i * NCT + lane];
    int bidx = pidx[(size_t)i * NCT + lane];
#pragma unroll
    for (int msk = 1; msk < 64; msk <<= 1) {
        float ob = __shfl_xor(best, msk);
        int oi = __shfl_xor(bidx, msk);
        if (ob > best || (ob == best && oi < bidx)) { best = ob; bidx = oi; }
    }

    const float ra = rnA[i];
    const float rp = rnP[i];
    const float rn = rnP[bidx];
    const float4* av = (const float4*)(x + (size_t)i * (2 * Dn));
    const float4* pv = (const float4*)(x + (size_t)i * (2 * Dn) + Dn);
    const float4* nv = (const float4*)(x + (size_t)bidx * (2 * Dn) + Dn);
    float pos = 0.f, ng = 0.f;
#pragma unroll
    for (int c = 0; c < 2; ++c) {
        const int idx = lane + c * 64;
        float4 a4 = av[idx], p4 = pv[idx], n4 = nv[idx];
        float u;
        u = a4.x * ra - p4.x * rp + EPSP; pos += u * u;
        u = a4.y * ra - p4.y * rp + EPSP; pos += u * u;
        u = a4.z * ra - p4.z * rp + EPSP; pos += u * u;
        u = a4.w * ra - p4.w * rp + EPSP; pos += u * u;
        u = a4.x * ra - n4.x * rn + EPSP; ng += u * u;
        u = a4.y * ra - n4.y * rn + EPSP; ng += u * u;
        u = a4.z * ra - n4.z * rn + EPSP; ng += u * u;
        u = a4.w * ra - n4.w * rn + EPSP; ng += u * u;
    }
#pragma unroll
    for (int msk = 1; msk < 64; msk <<= 1) {
        pos += __shfl_xor(pos, msk);
        ng += __shfl_xor(ng, msk);
    }
    if (lane == 0) rowloss[i] = fmaxf(pos - ng + MARG, 0.f);
}

// ---------------------------------------------------------------------------
// K4: mean over 8192 row losses -> scalar out (deterministic, no atomics)
// ---------------------------------------------------------------------------
__global__ __launch_bounds__(1024) void k_final(
    const float* __restrict__ rowloss, float* __restrict__ out)
{
    __shared__ float sm[16];
    float s = 0.f;
    for (int k = threadIdx.x; k < Bn; k += 1024) s += rowloss[k];
#pragma unroll
    for (int msk = 1; msk < 64; msk <<= 1) s += __shfl_xor(s, msk);
    if ((threadIdx.x & 63) == 0) sm[threadIdx.x >> 6] = s;
    __syncthreads();
    if (threadIdx.x == 0) {
        float tot = 0.f;
#pragma unroll
        for (int w = 0; w < 16; ++w) tot += sm[w];
        out[0] = tot * (1.0f / Bn);
    }
}

extern "C" void kernel_launch(void* const* d_in, const int* in_sizes, int n_in,
                              void* d_out, int out_size, void* d_ws, size_t ws_size,
                              hipStream_t stream)
{
    const float* x = (const float*)d_in[0];
    char* ws = (char*)d_ws;
    // workspace layout (bytes):
    uint16_t* a_bf    = (uint16_t*)(ws + 0);         // 8 MB
    uint16_t* p_bf    = (uint16_t*)(ws + 8388608);   // 8 MB
    float*    rnA     = (float*)(ws + 16777216);     // 32 KB
    float*    rnP     = (float*)(ws + 16809984);     // 32 KB
    float*    cterm   = (float*)(ws + 16842752);     // 32 KB
    float*    pval    = (float*)(ws + 16875520);     // 2 MB
    int*      pidx    = (int*)(ws + 18972672);       // 2 MB
    float*    rowloss = (float*)(ws + 21069824);     // 32 KB (total ~21.1 MB)
    float*    out     = (float*)d_out;

    k_normalize<<<4096, 256, 0, stream>>>(x, a_bf, p_bf, rnA, rnP, cterm);
    k_gemm_argmax<<<dim3(NCT, Bn / BM), 256, 0, stream>>>(a_bf, p_bf, cterm, pval, pidx);
    k_rowloss<<<2048, 256, 0, stream>>>(x, rnA, rnP, pval, pidx, rowloss);
    k_final<<<1, 1024, 0, stream>>>(rowloss, out);
}